// Round 1
// baseline (403.844 us; speedup 1.0000x reference)
//
#include <hip/hip_runtime.h>

// BatchSRU: L=2048, B=8, D=128, NB=16
// Plan: K1 transposes x (L,B,D,NB) -> xT[k][b][l][d] as fp16 hi/lo (precision split).
//       K2 fuses per-(b,k,dhalf) GEMM (W in registers, fp16 hi/lo, 3-product MFMA)
//       with the serial scan (producer/consumer: 4 GEMM waves + 1 scan wave).

typedef float f32x4 __attribute__((ext_vector_type(4)));
typedef _Float16 f16x8 __attribute__((ext_vector_type(8)));

#define LDIM 2048
#define XT_ELEMS 33554432  // 2048*8*128*16

// ---------------- Kernel 1: transpose + fp16 hi/lo split ----------------
__global__ __launch_bounds__(256) void k_prep(const float* __restrict__ x,
                                              _Float16* __restrict__ xh,
                                              _Float16* __restrict__ xl) {
  __shared__ _Float16 sh[16][136];  // [k][d], padded rows for bank spread
  __shared__ _Float16 sl[16][136];
  const int bid = blockIdx.x;  // = l*8 + b
  const int b = bid & 7, l = bid >> 3;
  const int t = threadIdx.x;
  const float* src = x + (size_t)bid * 2048;  // (d,k) innermost, contiguous
  const int d = t >> 1, k0 = (t & 1) * 8;
  f32x4 v0 = *(const f32x4*)(src + d * 16 + k0);
  f32x4 v1 = *(const f32x4*)(src + d * 16 + k0 + 4);
#pragma unroll
  for (int i = 0; i < 8; ++i) {
    float xv = (i < 4) ? v0[i] : v1[i - 4];
    _Float16 h = (_Float16)xv;
    _Float16 lo = (_Float16)(xv - (float)h);
    sh[k0 + i][d] = h;
    sl[k0 + i][d] = lo;
  }
  __syncthreads();
  const int k = t >> 4, dc = t & 15;
  int4 ah = *(const int4*)&sh[k][dc * 8];
  int4 al = *(const int4*)&sl[k][dc * 8];
  size_t o = ((size_t)(k * 8 + b) * 2048 + (size_t)l) * 128 + dc * 8;
  *(int4*)(xh + o) = ah;
  *(int4*)(xl + o) = al;
}

// ---------------- Kernel 2: fused GEMM + scan ----------------
// grid 256 = (b,k,j): b = bid&7 (XCD pin), k = (bid>>3)&15, j = bid>>7.
// 5 waves: waves 0-3 GEMM (12 col-tiles of U^T: x~|f|r * 64 cols), wave 4 scan.
__global__ __launch_bounds__(320, 1) void k_sru(
    const _Float16* __restrict__ xh, const _Float16* __restrict__ xl,
    const float* __restrict__ W, const float* __restrict__ bias,
    float* __restrict__ out) {
  // x tiles: [buf][row m][128 d as 16 chunks of 8 halves], chunk-XOR-swizzled
  __shared__ _Float16 Xh[3][16][128];
  __shared__ _Float16 Xl[3][16][128];
  // U^T: [192 cols rho][16 rows m], 4-word-rotated by ((rho>>1)&3). Reused for W staging.
  __shared__ float Ut[2][192 * 16];

  const int bid = blockIdx.x;
  const int b = bid & 7;
  const int k = (bid >> 3) & 15;
  const int j = bid >> 7;  // d-half
  const int tid = threadIdx.x;
  const int wl = tid & 63;
  const int w = tid >> 6;  // wave 0..4
  const bool gemmw = (w < 4);

  // ---- W[k] half-columns -> register fragments (fp16 hi/lo) ----
  // B-frag for mfma_f32_16x16x32_f16: lane = n + 16*g holds B[32s+8g+i][colbase+n], i=0..7
  f16x8 BH[3][4], BL[3][4];
  {
    const float* Wk = W + (size_t)k * (128 * 384);
    float* Wst = &Ut[0][0];  // 6144 floats = one 32-row x 192-col chunk
#pragma unroll
    for (int s = 0; s < 4; ++s) {
      for (int e = tid; e < 32 * 192; e += 320) {
        int dl = e / 192;
        int c = e - dl * 192;
        int cti = c >> 6, cc = c & 63;
        Wst[e] = Wk[(size_t)(32 * s + dl) * 384 + cti * 128 + j * 64 + cc];
      }
      __syncthreads();
      if (gemmw) {
        int g4 = wl >> 4, n = wl & 15;
#pragma unroll
        for (int cti = 0; cti < 3; ++cti) {
#pragma unroll
          for (int ii = 0; ii < 8; ++ii) {
            float v = Wst[(8 * g4 + ii) * 192 + 64 * cti + 16 * w + n];
            _Float16 h = (_Float16)v;
            BH[cti][s][ii] = h;
            BL[cti][s][ii] = (_Float16)(v - (float)h);
          }
        }
      }
      __syncthreads();
    }
  }

  float biasF = 0.f, biasR = 0.f;
  if (gemmw) {
    int n = wl & 15;
    biasF = bias[k * 256 + j * 64 + 16 * w + n];
    biasR = bias[k * 256 + 128 + j * 64 + 16 * w + n];
  }
  float creg = 0.f;  // scan state (wave 4)

  const size_t xbase = (size_t)(k * 8 + b) * 2048 * 128;

  auto stage = [&](int tile, int nb) {
    // wave w stages rows [4w,4w+4): dest linear, src chunk-XOR pre-swizzled
    int m = 4 * w + (wl >> 4);
    int tslot = wl & 15;
    int sc = tslot ^ (m & 7);
    size_t so = xbase + (size_t)(tile * 16 + m) * 128 + sc * 8;
    __builtin_amdgcn_global_load_lds(
        (const __attribute__((address_space(1))) void*)(xh + so),
        (__attribute__((address_space(3))) void*)&Xh[nb][4 * w][0], 16, 0, 0);
    __builtin_amdgcn_global_load_lds(
        (const __attribute__((address_space(1))) void*)(xl + so),
        (__attribute__((address_space(3))) void*)&Xl[nb][4 * w][0], 16, 0, 0);
  };

  auto gemm = [&](int tile, int nb, int ub) {
    (void)tile;
    f32x4 acc0 = {0.f, 0.f, 0.f, 0.f}, acc1 = acc0, acc2 = acc0;
    const int m = wl & 15, g = wl >> 4;
#pragma unroll
    for (int s = 0; s < 4; ++s) {
      int slot = (4 * s + g) ^ (m & 7);
      f16x8 ah = *(const f16x8*)&Xh[nb][m][slot * 8];
      f16x8 al = *(const f16x8*)&Xl[nb][m][slot * 8];
      acc0 = __builtin_amdgcn_mfma_f32_16x16x32_f16(ah, BH[0][s], acc0, 0, 0, 0);
      acc1 = __builtin_amdgcn_mfma_f32_16x16x32_f16(ah, BH[1][s], acc1, 0, 0, 0);
      acc2 = __builtin_amdgcn_mfma_f32_16x16x32_f16(ah, BH[2][s], acc2, 0, 0, 0);
      acc0 = __builtin_amdgcn_mfma_f32_16x16x32_f16(al, BH[0][s], acc0, 0, 0, 0);
      acc1 = __builtin_amdgcn_mfma_f32_16x16x32_f16(al, BH[1][s], acc1, 0, 0, 0);
      acc2 = __builtin_amdgcn_mfma_f32_16x16x32_f16(al, BH[2][s], acc2, 0, 0, 0);
      acc0 = __builtin_amdgcn_mfma_f32_16x16x32_f16(ah, BL[0][s], acc0, 0, 0, 0);
      acc1 = __builtin_amdgcn_mfma_f32_16x16x32_f16(ah, BL[1][s], acc1, 0, 0, 0);
      acc2 = __builtin_amdgcn_mfma_f32_16x16x32_f16(ah, BL[2][s], acc2, 0, 0, 0);
    }
    // post: bias+sigmoid for f/r parts, write U^T (rotated)
    const int n = m;
    const int off = (4 * g + ((n >> 1) & 3) * 4) & 15;
#pragma unroll
    for (int e = 0; e < 4; ++e) {
      acc1[e] = 1.f / (1.f + __expf(-(acc1[e] + biasF)));
      acc2[e] = 1.f / (1.f + __expf(-(acc2[e] + biasR)));
    }
    {
      int rho = 16 * w + n;  // x~ part
      *(f32x4*)&Ut[ub][rho * 16 + off] = acc0;
      *(f32x4*)&Ut[ub][(64 + rho) * 16 + off] = acc1;
      *(f32x4*)&Ut[ub][(128 + rho) * 16 + off] = acc2;
    }
  };

  auto scan = [&](int tile, int nb, int ub) {
    const int d = wl;
    const int rot4 = ((d >> 1) & 3) * 4;
    f32x4 xt4[4], ff4[4], rr4[4];
#pragma unroll
    for (int sp = 0; sp < 4; ++sp) {
      int off = (4 * sp + rot4) & 15;
      xt4[sp] = *(const f32x4*)&Ut[ub][d * 16 + off];
      ff4[sp] = *(const f32x4*)&Ut[ub][(64 + d) * 16 + off];
      rr4[sp] = *(const f32x4*)&Ut[ub][(128 + d) * 16 + off];
    }
    float xv[16];
    const int cbase = j * 8 + (d >> 3);
#pragma unroll
    for (int m2 = 0; m2 < 16; ++m2) {
      int slot = cbase ^ (m2 & 7);
      float hi = (float)Xh[nb][m2][slot * 8 + (d & 7)];
      float lo = (float)Xl[nb][m2][slot * 8 + (d & 7)];
      xv[m2] = hi + lo;
    }
    float* op = out + (size_t)tile * 16 * 16384 + b * 2048 + (j * 64 + d) * 16 + k;
#pragma unroll
    for (int m2 = 0; m2 < 16; ++m2) {
      float xt = xt4[m2 >> 2][m2 & 3];
      float f = ff4[m2 >> 2][m2 & 3];
      float r = rr4[m2 >> 2][m2 & 3];
      creg = xt + f * (creg - xt);  // c = f*c + (1-f)*x~
      float x0 = xv[m2];
      op[(size_t)m2 * 16384] = x0 + r * (creg - x0);  // h = r*c + (1-r)*x
    }
  };

  if (gemmw) stage(0, 0);
  __syncthreads();

  for (int i = 0; i <= 128; ++i) {
    if (gemmw) {
      if (i < 128) {
        if (i < 127) stage(i + 1, (i + 1) % 3);
        gemm(i, i % 3, i & 1);
      }
    } else {
      if (i >= 1) scan(i - 1, (i - 1) % 3, (i - 1) & 1);
    }
    __syncthreads();
  }
}

extern "C" void kernel_launch(void* const* d_in, const int* in_sizes, int n_in,
                              void* d_out, int out_size, void* d_ws, size_t ws_size,
                              hipStream_t stream) {
  (void)in_sizes; (void)n_in; (void)out_size; (void)ws_size;
  const float* x = (const float*)d_in[0];
  const float* W = (const float*)d_in[1];
  const float* bias = (const float*)d_in[2];
  float* out = (float*)d_out;
  _Float16* xhp = (_Float16*)d_ws;           // needs 2*64 MiB of workspace
  _Float16* xlp = xhp + (size_t)XT_ELEMS;
  k_prep<<<16384, 256, 0, stream>>>(x, xhp, xlp);
  k_sru<<<256, 320, 0, stream>>>(xhp, xlp, W, bias, out);
}